// Round 4
// baseline (195.842 us; speedup 1.0000x reference)
//
#include <hip/hip_runtime.h>

typedef float f32x4 __attribute__((ext_vector_type(4)));

// Problem constants
#define C_CH 256
#define S_DIM 16
#define HW 128
#define RANK 8
#define NCOPY 16

// ws float offsets
#define OFF_PC 0       // [16][256] per-copy channel partial sums
#define OFF_PS 4096    // [16][16]
#define OFF_PI 4352    // [16][128]  axis-3 partials (Wv source)
#define OFF_PJ 6400    // [16][128]  axis-4 partials (Hv source)
#define OFF_CF 8448    // [8][256]  coef * sigmoid(W1@Cv)
#define OFF_SF 10496   // [8][16]
#define OFF_HF 10624   // [8][128]  sigmoid(W3@Hv)
#define OFF_WF 11648   // [8][128]  sigmoid(W4@Wv)

__global__ __launch_bounds__(256) void k_init(float* __restrict__ ws) {
    int idx = blockIdx.x * 256 + threadIdx.x;
    if (idx < OFF_CF) ws[idx] = 0.f;
}

// Grid 1024: each block reduces 4 consecutive (c,s) slabs (same c) AND
// copies them to out[:256] (the concat identity half) with nt stores.
// Mixed R+W stream keeps HBM busier than the old pure-read version.
__global__ __launch_bounds__(256) void k_reduce(const float* __restrict__ x,
                                                float* __restrict__ out,
                                                float* __restrict__ ws) {
    int b = blockIdx.x;
    int c = b >> 2;
    int s0 = (b & 3) * 4;
    int t = threadIdx.x;
    int lane = t & 31;
    int rg = t >> 5;          // row group 0..7
    int j0 = lane * 4;        // columns j0..j0+3

    float colacc[4] = {0.f, 0.f, 0.f, 0.f};
    float rowacc[16] = {0.f};
    float tot[4] = {0.f, 0.f, 0.f, 0.f};

    for (int q = 0; q < 4; ++q) {
        size_t slab = (size_t)(b * 4 + q) * 16384;
        const f32x4* xs = reinterpret_cast<const f32x4*>(x + slab);
        f32x4* o1 = reinterpret_cast<f32x4*>(out + slab);
#pragma unroll
        for (int k = 0; k < 16; ++k) {
            f32x4 v = xs[k * 256 + t];      // row k*8+rg, cols j0..j0+3
            __builtin_nontemporal_store(v, &o1[k * 256 + t]);
            colacc[0] += v.x; colacc[1] += v.y;
            colacc[2] += v.z; colacc[3] += v.w;
            float s4 = (v.x + v.y) + (v.z + v.w);
            rowacc[k] += s4;
            tot[q] += s4;
        }
    }

    __shared__ float ldsr[128 * 33];   // [row][lane], pad 33
    __shared__ float ldsc[128 * 9];    // [col][rg],   pad 9
    __shared__ float ldst[4][4];       // [wave][q]

#pragma unroll
    for (int k = 0; k < 16; ++k) ldsr[(k * 8 + rg) * 33 + lane] = rowacc[k];
#pragma unroll
    for (int jj = 0; jj < 4; ++jj) ldsc[(j0 + jj) * 9 + rg] = colacc[jj];
#pragma unroll
    for (int q = 0; q < 4; ++q) {
        float v = tot[q];
        for (int d = 32; d > 0; d >>= 1) v += __shfl_down(v, d, 64);
        if ((t & 63) == 0) ldst[t >> 6][q] = v;
    }
    __syncthreads();

    int copy = b & (NCOPY - 1);
    if (t < 128) {
        float rsum = 0.f;
#pragma unroll
        for (int l = 0; l < 32; ++l) rsum += ldsr[t * 33 + l];
        atomicAdd(&ws[OFF_PI + copy * 128 + t], rsum);
    } else {
        int j = t - 128;
        float csum = 0.f;
#pragma unroll
        for (int g = 0; g < 8; ++g) csum += ldsc[j * 9 + g];
        atomicAdd(&ws[OFF_PJ + copy * 128 + j], csum);
    }
    if (t < 4) {
        float sv = ldst[0][t] + ldst[1][t] + ldst[2][t] + ldst[3][t];
        atomicAdd(&ws[OFF_PS + copy * 16 + s0 + t], sv);
    }
    if (t == 8) {
        float cv = 0.f;
#pragma unroll
        for (int w = 0; w < 4; ++w)
#pragma unroll
            for (int q = 0; q < 4; ++q) cv += ldst[w][q];
        atomicAdd(&ws[OFF_PC + copy * 256 + c], cv);
    }
}

// Finish means + softmax coef + all sigmoid matvec rows. Grid = 17 blocks.
__global__ __launch_bounds__(256) void k_factors(const float* __restrict__ W1,
                                                 const float* __restrict__ W2,
                                                 const float* __restrict__ W3,
                                                 const float* __restrict__ W4,
                                                 const float* __restrict__ lam,
                                                 float* __restrict__ ws) {
    __shared__ float mC[256], mS[16], mW[128], mH[128];
    int t = threadIdx.x;
    for (int idx = t; idx < 528; idx += 256) {
        float acc = 0.f;
        if (idx < 256) {
            for (int cp = 0; cp < NCOPY; ++cp) acc += ws[OFF_PC + cp * 256 + idx];
            mC[idx] = acc * (1.f / (S_DIM * 16384.f));
        } else if (idx < 272) {
            int q = idx - 256;
            for (int cp = 0; cp < NCOPY; ++cp) acc += ws[OFF_PS + cp * 16 + q];
            mS[q] = acc * (1.f / (C_CH * 16384.f));
        } else if (idx < 400) {
            int q = idx - 272;
            for (int cp = 0; cp < NCOPY; ++cp) acc += ws[OFF_PI + cp * 128 + q];
            mW[q] = acc * (1.f / (C_CH * S_DIM * 128.f));
        } else {
            int q = idx - 400;
            for (int cp = 0; cp < NCOPY; ++cp) acc += ws[OFF_PJ + cp * 128 + q];
            mH[q] = acc * (1.f / (C_CH * S_DIM * 128.f));
        }
    }
    __syncthreads();

    // softmax(lam)[0], computed redundantly per thread (8 elements)
    float m = lam[0];
    for (int r = 1; r < RANK; ++r) m = fmaxf(m, lam[r]);
    float den = 0.f;
    for (int r = 0; r < RANK; ++r) den += expf(lam[r] - m);
    float coef = expf(lam[0] - m) / den;

    int rid = blockIdx.x * 256 + t;
    if (rid < 2048) {                       // cf: 8 x 256 rows, len 256
        int r = rid >> 8, i = rid & 255;
        const float* w = W1 + r * 65536 + i * 256;
        float d = 0.f;
        for (int k = 0; k < 256; ++k) d += w[k] * mC[k];
        ws[OFF_CF + rid] = coef / (1.f + expf(-d));
    } else if (rid < 2176) {                // sf: 8 x 16 rows, len 16
        int q = rid - 2048;
        int r = q >> 4, i = q & 15;
        const float* w = W2 + r * 256 + i * 16;
        float d = 0.f;
        for (int k = 0; k < 16; ++k) d += w[k] * mS[k];
        ws[OFF_SF + q] = 1.f / (1.f + expf(-d));
    } else if (rid < 3200) {                // hf = sigmoid(W3 @ Hv)
        int q = rid - 2176;
        int r = q >> 7, i = q & 127;
        const float* w = W3 + r * 16384 + i * 128;
        float d = 0.f;
        for (int k = 0; k < 128; ++k) d += w[k] * mH[k];
        ws[OFF_HF + q] = 1.f / (1.f + expf(-d));
    } else if (rid < 4224) {                // wf = sigmoid(W4 @ Wv)
        int q = rid - 3200;
        int r = q >> 7, i = q & 127;
        const float* w = W4 + r * 16384 + i * 128;
        float d = 0.f;
        for (int k = 0; k < 128; ++k) d += w[k] * mW[k];
        ws[OFF_WF + q] = 1.f / (1.f + expf(-d));
    }
}

// One block per (c,s) slab: out[256:] = relu(x * t1) only (identity half
// was written by k_reduce). Reads of x are L3-candidates; nt stores.
__global__ __launch_bounds__(256) void k_output(const float* __restrict__ x,
                                                const float* __restrict__ ws,
                                                float* __restrict__ out) {
    int b = blockIdx.x;
    int c = b >> 4, s = b & 15;
    int t = threadIdx.x;

    __shared__ float hb[128 * 8];   // hb[i*8+r] = hf[r][i]
    __shared__ float wb[128 * 8];   // wb[j*8+r] = cf'[r][c]*sf[r][s]*wf[r][j]

    const float* cf = ws + OFF_CF;
    const float* sf = ws + OFF_SF;
    const float* hf = ws + OFF_HF;
    const float* wf = ws + OFF_WF;

    for (int idx = t; idx < 1024; idx += 256) {
        int r = idx & 7, p = idx >> 3;
        hb[idx] = hf[r * 128 + p];
        wb[idx] = cf[r * 256 + c] * sf[r * 16 + s] * wf[r * 128 + p];
    }
    __syncthreads();

    int j0 = (t & 31) * 4, rg = t >> 5;
    float wreg[4][8];
#pragma unroll
    for (int jj = 0; jj < 4; ++jj)
#pragma unroll
        for (int r = 0; r < 8; ++r) wreg[jj][r] = wb[(j0 + jj) * 8 + r];

    size_t slab = (size_t)b * 16384;
    const f32x4* xs = reinterpret_cast<const f32x4*>(x + slab);
    f32x4* o2 = reinterpret_cast<f32x4*>(out + (size_t)67108864 + slab);

    for (int k = 0; k < 16; ++k) {
        int i = k * 8 + rg;
        int vidx = i * 32 + (t & 31);
        f32x4 v = xs[vidx];
        float h[8];
#pragma unroll
        for (int r = 0; r < 8; ++r) h[r] = hb[i * 8 + r];   // broadcast reads
        float t0 = 0.f, t1 = 0.f, t2 = 0.f, t3 = 0.f;
#pragma unroll
        for (int r = 0; r < 8; ++r) {
            t0 += h[r] * wreg[0][r];
            t1 += h[r] * wreg[1][r];
            t2 += h[r] * wreg[2][r];
            t3 += h[r] * wreg[3][r];
        }
        f32x4 y;
        y.x = fmaxf(v.x * t0, 0.f);
        y.y = fmaxf(v.y * t1, 0.f);
        y.z = fmaxf(v.z * t2, 0.f);
        y.w = fmaxf(v.w * t3, 0.f);
        __builtin_nontemporal_store(y, &o2[vidx]);
    }
}

extern "C" void kernel_launch(void* const* d_in, const int* in_sizes, int n_in,
                              void* d_out, int out_size, void* d_ws, size_t ws_size,
                              hipStream_t stream) {
    const float* x   = (const float*)d_in[0];
    const float* W1  = (const float*)d_in[1];
    const float* W2  = (const float*)d_in[2];
    const float* W3  = (const float*)d_in[3];
    const float* W4  = (const float*)d_in[4];
    const float* lam = (const float*)d_in[5];
    float* ws  = (float*)d_ws;
    float* out = (float*)d_out;

    k_init<<<33, 256, 0, stream>>>(ws);                         // zero 8448 partials
    k_reduce<<<1024, 256, 0, stream>>>(x, out, ws);             // means + copy half
    k_factors<<<17, 256, 0, stream>>>(W1, W2, W3, W4, lam, ws);
    k_output<<<4096, 256, 0, stream>>>(x, ws, out);             // relu(x*t1) half
}

// Round 5
// 195.327 us; speedup vs baseline: 1.0026x; 1.0026x over previous
//
#include <hip/hip_runtime.h>

typedef float f32x4 __attribute__((ext_vector_type(4)));

// Problem constants
#define C_CH 256
#define S_DIM 16
#define HW 128
#define RANK 8
#define NCOPY 16

// ws float offsets
#define OFF_PC 0       // [16][256] per-copy channel partial sums
#define OFF_PS 4096    // [16][16]
#define OFF_PI 4352    // [16][128]  axis-3 partials (Wv source)
#define OFF_PJ 6400    // [16][128]  axis-4 partials (Hv source)
#define OFF_CF 8448    // [8][256]  coef * sigmoid(W1@Cv)
#define OFF_SF 10496   // [8][16]
#define OFF_HF 10624   // [8][128]  sigmoid(W3@Hv)
#define OFF_WF 11648   // [8][128]  sigmoid(W4@Wv)

__global__ __launch_bounds__(256) void k_init(float* __restrict__ ws) {
    int idx = blockIdx.x * 256 + threadIdx.x;
    if (idx < OFF_CF) ws[idx] = 0.f;
}

// Grid 1024: each block reduces 4 consecutive (c,s) slabs (same c) AND
// copies them to out[:256] (the concat identity half) with nt stores.
// Forward order: leaves the TAIL of x resident in L3 for k_output.
__global__ __launch_bounds__(256) void k_reduce(const float* __restrict__ x,
                                                float* __restrict__ out,
                                                float* __restrict__ ws) {
    int b = blockIdx.x;
    int c = b >> 2;
    int s0 = (b & 3) * 4;
    int t = threadIdx.x;
    int lane = t & 31;
    int rg = t >> 5;          // row group 0..7
    int j0 = lane * 4;        // columns j0..j0+3

    float colacc[4] = {0.f, 0.f, 0.f, 0.f};
    float rowacc[16] = {0.f};
    float tot[4] = {0.f, 0.f, 0.f, 0.f};

    for (int q = 0; q < 4; ++q) {
        size_t slab = (size_t)(b * 4 + q) * 16384;
        const f32x4* xs = reinterpret_cast<const f32x4*>(x + slab);
        f32x4* o1 = reinterpret_cast<f32x4*>(out + slab);
#pragma unroll
        for (int k = 0; k < 16; ++k) {
            f32x4 v = xs[k * 256 + t];      // row k*8+rg, cols j0..j0+3
            __builtin_nontemporal_store(v, &o1[k * 256 + t]);
            colacc[0] += v.x; colacc[1] += v.y;
            colacc[2] += v.z; colacc[3] += v.w;
            float s4 = (v.x + v.y) + (v.z + v.w);
            rowacc[k] += s4;
            tot[q] += s4;
        }
    }

    __shared__ float ldsr[128 * 33];   // [row][lane], pad 33
    __shared__ float ldsc[128 * 9];    // [col][rg],   pad 9
    __shared__ float ldst[4][4];       // [wave][q]

#pragma unroll
    for (int k = 0; k < 16; ++k) ldsr[(k * 8 + rg) * 33 + lane] = rowacc[k];
#pragma unroll
    for (int jj = 0; jj < 4; ++jj) ldsc[(j0 + jj) * 9 + rg] = colacc[jj];
#pragma unroll
    for (int q = 0; q < 4; ++q) {
        float v = tot[q];
        for (int d = 32; d > 0; d >>= 1) v += __shfl_down(v, d, 64);
        if ((t & 63) == 0) ldst[t >> 6][q] = v;
    }
    __syncthreads();

    int copy = b & (NCOPY - 1);
    if (t < 128) {
        float rsum = 0.f;
#pragma unroll
        for (int l = 0; l < 32; ++l) rsum += ldsr[t * 33 + l];
        atomicAdd(&ws[OFF_PI + copy * 128 + t], rsum);
    } else {
        int j = t - 128;
        float csum = 0.f;
#pragma unroll
        for (int g = 0; g < 8; ++g) csum += ldsc[j * 9 + g];
        atomicAdd(&ws[OFF_PJ + copy * 128 + j], csum);
    }
    if (t < 4) {
        float sv = ldst[0][t] + ldst[1][t] + ldst[2][t] + ldst[3][t];
        atomicAdd(&ws[OFF_PS + copy * 16 + s0 + t], sv);
    }
    if (t == 8) {
        float cv = 0.f;
#pragma unroll
        for (int w = 0; w < 4; ++w)
#pragma unroll
            for (int q = 0; q < 4; ++q) cv += ldst[w][q];
        atomicAdd(&ws[OFF_PC + copy * 256 + c], cv);
    }
}

// Finish means + softmax coef + all sigmoid matvec rows. Grid = 17 blocks.
__global__ __launch_bounds__(256) void k_factors(const float* __restrict__ W1,
                                                 const float* __restrict__ W2,
                                                 const float* __restrict__ W3,
                                                 const float* __restrict__ W4,
                                                 const float* __restrict__ lam,
                                                 float* __restrict__ ws) {
    __shared__ float mC[256], mS[16], mW[128], mH[128];
    int t = threadIdx.x;
    for (int idx = t; idx < 528; idx += 256) {
        float acc = 0.f;
        if (idx < 256) {
            for (int cp = 0; cp < NCOPY; ++cp) acc += ws[OFF_PC + cp * 256 + idx];
            mC[idx] = acc * (1.f / (S_DIM * 16384.f));
        } else if (idx < 272) {
            int q = idx - 256;
            for (int cp = 0; cp < NCOPY; ++cp) acc += ws[OFF_PS + cp * 16 + q];
            mS[q] = acc * (1.f / (C_CH * 16384.f));
        } else if (idx < 400) {
            int q = idx - 272;
            for (int cp = 0; cp < NCOPY; ++cp) acc += ws[OFF_PI + cp * 128 + q];
            mW[q] = acc * (1.f / (C_CH * S_DIM * 128.f));
        } else {
            int q = idx - 400;
            for (int cp = 0; cp < NCOPY; ++cp) acc += ws[OFF_PJ + cp * 128 + q];
            mH[q] = acc * (1.f / (C_CH * S_DIM * 128.f));
        }
    }
    __syncthreads();

    // softmax(lam)[0], computed redundantly per thread (8 elements)
    float m = lam[0];
    for (int r = 1; r < RANK; ++r) m = fmaxf(m, lam[r]);
    float den = 0.f;
    for (int r = 0; r < RANK; ++r) den += expf(lam[r] - m);
    float coef = expf(lam[0] - m) / den;

    int rid = blockIdx.x * 256 + t;
    if (rid < 2048) {                       // cf: 8 x 256 rows, len 256
        int r = rid >> 8, i = rid & 255;
        const float* w = W1 + r * 65536 + i * 256;
        float d = 0.f;
        for (int k = 0; k < 256; ++k) d += w[k] * mC[k];
        ws[OFF_CF + rid] = coef / (1.f + expf(-d));
    } else if (rid < 2176) {                // sf: 8 x 16 rows, len 16
        int q = rid - 2048;
        int r = q >> 4, i = q & 15;
        const float* w = W2 + r * 256 + i * 16;
        float d = 0.f;
        for (int k = 0; k < 16; ++k) d += w[k] * mS[k];
        ws[OFF_SF + q] = 1.f / (1.f + expf(-d));
    } else if (rid < 3200) {                // hf = sigmoid(W3 @ Hv)
        int q = rid - 2176;
        int r = q >> 7, i = q & 127;
        const float* w = W3 + r * 16384 + i * 128;
        float d = 0.f;
        for (int k = 0; k < 128; ++k) d += w[k] * mH[k];
        ws[OFF_HF + q] = 1.f / (1.f + expf(-d));
    } else if (rid < 4224) {                // wf = sigmoid(W4 @ Wv)
        int q = rid - 3200;
        int r = q >> 7, i = q & 127;
        const float* w = W4 + r * 16384 + i * 128;
        float d = 0.f;
        for (int k = 0; k < 128; ++k) d += w[k] * mW[k];
        ws[OFF_WF + q] = 1.f / (1.f + expf(-d));
    }
}

// One block per (c,s) slab: out[256:] = relu(x * t1). REVERSE slab order:
// k_reduce streamed x forward, so the tail (~256 MB) is L3-resident when
// this kernel starts. Reading backward turns the re-read into L3 hits;
// nt stores don't evict it.
__global__ __launch_bounds__(256) void k_output(const float* __restrict__ x,
                                                const float* __restrict__ ws,
                                                float* __restrict__ out) {
    int b = 4095 - (int)blockIdx.x;     // reverse order for L3 reuse
    int c = b >> 4, s = b & 15;
    int t = threadIdx.x;

    __shared__ float hb[128 * 8];   // hb[i*8+r] = hf[r][i]
    __shared__ float wb[128 * 8];   // wb[j*8+r] = cf'[r][c]*sf[r][s]*wf[r][j]

    const float* cf = ws + OFF_CF;
    const float* sf = ws + OFF_SF;
    const float* hf = ws + OFF_HF;
    const float* wf = ws + OFF_WF;

    for (int idx = t; idx < 1024; idx += 256) {
        int r = idx & 7, p = idx >> 3;
        hb[idx] = hf[r * 128 + p];
        wb[idx] = cf[r * 256 + c] * sf[r * 16 + s] * wf[r * 128 + p];
    }
    __syncthreads();

    int j0 = (t & 31) * 4, rg = t >> 5;
    float wreg[4][8];
#pragma unroll
    for (int jj = 0; jj < 4; ++jj)
#pragma unroll
        for (int r = 0; r < 8; ++r) wreg[jj][r] = wb[(j0 + jj) * 8 + r];

    size_t slab = (size_t)b * 16384;
    const f32x4* xs = reinterpret_cast<const f32x4*>(x + slab);
    f32x4* o2 = reinterpret_cast<f32x4*>(out + (size_t)67108864 + slab);

    for (int k = 0; k < 16; ++k) {
        int i = k * 8 + rg;
        int vidx = i * 32 + (t & 31);
        f32x4 v = xs[vidx];
        float h[8];
#pragma unroll
        for (int r = 0; r < 8; ++r) h[r] = hb[i * 8 + r];   // broadcast reads
        float t0 = 0.f, t1 = 0.f, t2 = 0.f, t3 = 0.f;
#pragma unroll
        for (int r = 0; r < 8; ++r) {
            t0 += h[r] * wreg[0][r];
            t1 += h[r] * wreg[1][r];
            t2 += h[r] * wreg[2][r];
            t3 += h[r] * wreg[3][r];
        }
        f32x4 y;
        y.x = fmaxf(v.x * t0, 0.f);
        y.y = fmaxf(v.y * t1, 0.f);
        y.z = fmaxf(v.z * t2, 0.f);
        y.w = fmaxf(v.w * t3, 0.f);
        __builtin_nontemporal_store(y, &o2[vidx]);
    }
}

extern "C" void kernel_launch(void* const* d_in, const int* in_sizes, int n_in,
                              void* d_out, int out_size, void* d_ws, size_t ws_size,
                              hipStream_t stream) {
    const float* x   = (const float*)d_in[0];
    const float* W1  = (const float*)d_in[1];
    const float* W2  = (const float*)d_in[2];
    const float* W3  = (const float*)d_in[3];
    const float* W4  = (const float*)d_in[4];
    const float* lam = (const float*)d_in[5];
    float* ws  = (float*)d_ws;
    float* out = (float*)d_out;

    k_init<<<33, 256, 0, stream>>>(ws);                         // zero 8448 partials
    k_reduce<<<1024, 256, 0, stream>>>(x, out, ws);             // means + copy half
    k_factors<<<17, 256, 0, stream>>>(W1, W2, W3, W4, lam, ws);
    k_output<<<4096, 256, 0, stream>>>(x, ws, out);             // relu(x*t1) half, reversed
}

// Round 6
// 191.469 us; speedup vs baseline: 1.0228x; 1.0201x over previous
//
#include <hip/hip_runtime.h>

typedef float f32x4 __attribute__((ext_vector_type(4)));
typedef unsigned short u16x4 __attribute__((ext_vector_type(4)));

// Problem constants
#define C_CH 256
#define S_DIM 16
#define HW 128
#define RANK 8
#define NCOPY 16

// ws float offsets
#define OFF_PC 0       // [16][256] per-copy channel partial sums
#define OFF_PS 4096    // [16][16]
#define OFF_PI 4352    // [16][128]  axis-3 partials (Wv source)
#define OFF_PJ 6400    // [16][128]  axis-4 partials (Hv source)
#define OFF_CF 8448    // [8][256]  coef * sigmoid(W1@Cv)
#define OFF_SF 10496   // [8][16]
#define OFF_HF 10624   // [8][128]  sigmoid(W3@Hv)
#define OFF_WF 11648   // [8][128]  sigmoid(W4@Wv)
#define OFF_BF 16384   // float offset of bf16 x-copy (byte 65536), 134.2 MB

#define BF_WS_BYTES ((size_t)65536 + (size_t)67108864 * 2)

__device__ __forceinline__ unsigned short bf16rne(float f) {
    unsigned u = __float_as_uint(f);
    return (unsigned short)((u + 0x7FFFu + ((u >> 16) & 1u)) >> 16);
}

__global__ __launch_bounds__(256) void k_init(float* __restrict__ ws) {
    int idx = blockIdx.x * 256 + threadIdx.x;
    if (idx < OFF_CF) ws[idx] = 0.f;
}

// Grid 1024: each block reduces 4 consecutive (c,s) slabs (same c), copies
// them to out[:256] (nt), and (if WBF) emits a bf16 copy of x into ws with
// REGULAR stores so it allocates in the 256MB Infinity Cache. x-reads and
// out1-writes are non-temporal so they don't evict the bf16 copy.
template <bool WBF>
__global__ __launch_bounds__(256) void k_reduce(const float* __restrict__ x,
                                                float* __restrict__ out,
                                                float* __restrict__ ws) {
    int b = blockIdx.x;
    int c = b >> 2;
    int s0 = (b & 3) * 4;
    int t = threadIdx.x;
    int lane = t & 31;
    int rg = t >> 5;          // row group 0..7
    int j0 = lane * 4;        // columns j0..j0+3

    u16x4* bfp = reinterpret_cast<u16x4*>(
        reinterpret_cast<unsigned short*>(ws + OFF_BF));

    float colacc[4] = {0.f, 0.f, 0.f, 0.f};
    float rowacc[16] = {0.f};
    float tot[4] = {0.f, 0.f, 0.f, 0.f};

    for (int q = 0; q < 4; ++q) {
        size_t slab = (size_t)(b * 4 + q) * 16384;
        const f32x4* xs = reinterpret_cast<const f32x4*>(x + slab);
        f32x4* o1 = reinterpret_cast<f32x4*>(out + slab);
        u16x4* bf = bfp + (slab >> 2);
#pragma unroll
        for (int k = 0; k < 16; ++k) {
            f32x4 v = __builtin_nontemporal_load(&xs[k * 256 + t]);
            __builtin_nontemporal_store(v, &o1[k * 256 + t]);
            if (WBF) {
                u16x4 hv;
                hv.x = bf16rne(v.x);
                hv.y = bf16rne(v.y);
                hv.z = bf16rne(v.z);
                hv.w = bf16rne(v.w);
                bf[k * 256 + t] = hv;      // regular store -> L3 resident
            }
            colacc[0] += v.x; colacc[1] += v.y;
            colacc[2] += v.z; colacc[3] += v.w;
            float s4 = (v.x + v.y) + (v.z + v.w);
            rowacc[k] += s4;
            tot[q] += s4;
        }
    }

    __shared__ float ldsr[128 * 33];   // [row][lane], pad 33
    __shared__ float ldsc[128 * 9];    // [col][rg],   pad 9
    __shared__ float ldst[4][4];       // [wave][q]

#pragma unroll
    for (int k = 0; k < 16; ++k) ldsr[(k * 8 + rg) * 33 + lane] = rowacc[k];
#pragma unroll
    for (int jj = 0; jj < 4; ++jj) ldsc[(j0 + jj) * 9 + rg] = colacc[jj];
#pragma unroll
    for (int q = 0; q < 4; ++q) {
        float v = tot[q];
        for (int d = 32; d > 0; d >>= 1) v += __shfl_down(v, d, 64);
        if ((t & 63) == 0) ldst[t >> 6][q] = v;
    }
    __syncthreads();

    int copy = b & (NCOPY - 1);
    if (t < 128) {
        float rsum = 0.f;
#pragma unroll
        for (int l = 0; l < 32; ++l) rsum += ldsr[t * 33 + l];
        atomicAdd(&ws[OFF_PI + copy * 128 + t], rsum);
    } else {
        int j = t - 128;
        float csum = 0.f;
#pragma unroll
        for (int g = 0; g < 8; ++g) csum += ldsc[j * 9 + g];
        atomicAdd(&ws[OFF_PJ + copy * 128 + j], csum);
    }
    if (t < 4) {
        float sv = ldst[0][t] + ldst[1][t] + ldst[2][t] + ldst[3][t];
        atomicAdd(&ws[OFF_PS + copy * 16 + s0 + t], sv);
    }
    if (t == 8) {
        float cv = 0.f;
#pragma unroll
        for (int w = 0; w < 4; ++w)
#pragma unroll
            for (int q = 0; q < 4; ++q) cv += ldst[w][q];
        atomicAdd(&ws[OFF_PC + copy * 256 + c], cv);
    }
}

// Finish means + softmax coef + all sigmoid matvec rows. Grid = 17 blocks.
__global__ __launch_bounds__(256) void k_factors(const float* __restrict__ W1,
                                                 const float* __restrict__ W2,
                                                 const float* __restrict__ W3,
                                                 const float* __restrict__ W4,
                                                 const float* __restrict__ lam,
                                                 float* __restrict__ ws) {
    __shared__ float mC[256], mS[16], mW[128], mH[128];
    int t = threadIdx.x;
    for (int idx = t; idx < 528; idx += 256) {
        float acc = 0.f;
        if (idx < 256) {
            for (int cp = 0; cp < NCOPY; ++cp) acc += ws[OFF_PC + cp * 256 + idx];
            mC[idx] = acc * (1.f / (S_DIM * 16384.f));
        } else if (idx < 272) {
            int q = idx - 256;
            for (int cp = 0; cp < NCOPY; ++cp) acc += ws[OFF_PS + cp * 16 + q];
            mS[q] = acc * (1.f / (C_CH * 16384.f));
        } else if (idx < 400) {
            int q = idx - 272;
            for (int cp = 0; cp < NCOPY; ++cp) acc += ws[OFF_PI + cp * 128 + q];
            mW[q] = acc * (1.f / (C_CH * S_DIM * 128.f));
        } else {
            int q = idx - 400;
            for (int cp = 0; cp < NCOPY; ++cp) acc += ws[OFF_PJ + cp * 128 + q];
            mH[q] = acc * (1.f / (C_CH * S_DIM * 128.f));
        }
    }
    __syncthreads();

    // softmax(lam)[0], computed redundantly per thread (8 elements)
    float m = lam[0];
    for (int r = 1; r < RANK; ++r) m = fmaxf(m, lam[r]);
    float den = 0.f;
    for (int r = 0; r < RANK; ++r) den += expf(lam[r] - m);
    float coef = expf(lam[0] - m) / den;

    int rid = blockIdx.x * 256 + t;
    if (rid < 2048) {                       // cf: 8 x 256 rows, len 256
        int r = rid >> 8, i = rid & 255;
        const float* w = W1 + r * 65536 + i * 256;
        float d = 0.f;
        for (int k = 0; k < 256; ++k) d += w[k] * mC[k];
        ws[OFF_CF + rid] = coef / (1.f + expf(-d));
    } else if (rid < 2176) {                // sf: 8 x 16 rows, len 16
        int q = rid - 2048;
        int r = q >> 4, i = q & 15;
        const float* w = W2 + r * 256 + i * 16;
        float d = 0.f;
        for (int k = 0; k < 16; ++k) d += w[k] * mS[k];
        ws[OFF_SF + q] = 1.f / (1.f + expf(-d));
    } else if (rid < 3200) {                // hf = sigmoid(W3 @ Hv)
        int q = rid - 2176;
        int r = q >> 7, i = q & 127;
        const float* w = W3 + r * 16384 + i * 128;
        float d = 0.f;
        for (int k = 0; k < 128; ++k) d += w[k] * mH[k];
        ws[OFF_HF + q] = 1.f / (1.f + expf(-d));
    } else if (rid < 4224) {                // wf = sigmoid(W4 @ Wv)
        int q = rid - 3200;
        int r = q >> 7, i = q & 127;
        const float* w = W4 + r * 16384 + i * 128;
        float d = 0.f;
        for (int k = 0; k < 128; ++k) d += w[k] * mW[k];
        ws[OFF_WF + q] = 1.f / (1.f + expf(-d));
    }
}

// bf16 path: out[256:] = relu(x_bf16 * t1); x_bf16 read from ws (L3-hot).
__global__ __launch_bounds__(256) void k_output_bf(const float* __restrict__ ws,
                                                   float* __restrict__ out) {
    int b = blockIdx.x;
    int c = b >> 4, s = b & 15;
    int t = threadIdx.x;

    __shared__ float hb[128 * 8];   // hb[i*8+r] = hf[r][i]
    __shared__ float wb[128 * 8];   // wb[j*8+r] = cf'[r][c]*sf[r][s]*wf[r][j]

    const float* cf = ws + OFF_CF;
    const float* sf = ws + OFF_SF;
    const float* hf = ws + OFF_HF;
    const float* wf = ws + OFF_WF;

    for (int idx = t; idx < 1024; idx += 256) {
        int r = idx & 7, p = idx >> 3;
        hb[idx] = hf[r * 128 + p];
        wb[idx] = cf[r * 256 + c] * sf[r * 16 + s] * wf[r * 128 + p];
    }
    __syncthreads();

    int j0 = (t & 31) * 4, rg = t >> 5;
    float wreg[4][8];
#pragma unroll
    for (int jj = 0; jj < 4; ++jj)
#pragma unroll
        for (int r = 0; r < 8; ++r) wreg[jj][r] = wb[(j0 + jj) * 8 + r];

    const u16x4* bf = reinterpret_cast<const u16x4*>(
        reinterpret_cast<const unsigned short*>(ws + OFF_BF));
    size_t slab4 = (size_t)b * 4096;
    f32x4* o2 = reinterpret_cast<f32x4*>(out + (size_t)67108864 + (size_t)b * 16384);

    for (int k = 0; k < 16; ++k) {
        int i = k * 8 + rg;
        int vidx = i * 32 + (t & 31);
        u16x4 hv = bf[slab4 + vidx];
        f32x4 v;
        v.x = __uint_as_float((unsigned)hv.x << 16);
        v.y = __uint_as_float((unsigned)hv.y << 16);
        v.z = __uint_as_float((unsigned)hv.z << 16);
        v.w = __uint_as_float((unsigned)hv.w << 16);
        float h[8];
#pragma unroll
        for (int r = 0; r < 8; ++r) h[r] = hb[i * 8 + r];   // broadcast reads
        float t0 = 0.f, t1 = 0.f, t2 = 0.f, t3 = 0.f;
#pragma unroll
        for (int r = 0; r < 8; ++r) {
            t0 += h[r] * wreg[0][r];
            t1 += h[r] * wreg[1][r];
            t2 += h[r] * wreg[2][r];
            t3 += h[r] * wreg[3][r];
        }
        f32x4 y;
        y.x = fmaxf(v.x * t0, 0.f);
        y.y = fmaxf(v.y * t1, 0.f);
        y.z = fmaxf(v.z * t2, 0.f);
        y.w = fmaxf(v.w * t3, 0.f);
        __builtin_nontemporal_store(y, &o2[vidx]);
    }
}

// Fallback (ws too small): re-read fp32 x.
__global__ __launch_bounds__(256) void k_output_fp(const float* __restrict__ x,
                                                   const float* __restrict__ ws,
                                                   float* __restrict__ out) {
    int b = blockIdx.x;
    int c = b >> 4, s = b & 15;
    int t = threadIdx.x;

    __shared__ float hb[128 * 8];
    __shared__ float wb[128 * 8];

    const float* cf = ws + OFF_CF;
    const float* sf = ws + OFF_SF;
    const float* hf = ws + OFF_HF;
    const float* wf = ws + OFF_WF;

    for (int idx = t; idx < 1024; idx += 256) {
        int r = idx & 7, p = idx >> 3;
        hb[idx] = hf[r * 128 + p];
        wb[idx] = cf[r * 256 + c] * sf[r * 16 + s] * wf[r * 128 + p];
    }
    __syncthreads();

    int j0 = (t & 31) * 4, rg = t >> 5;
    float wreg[4][8];
#pragma unroll
    for (int jj = 0; jj < 4; ++jj)
#pragma unroll
        for (int r = 0; r < 8; ++r) wreg[jj][r] = wb[(j0 + jj) * 8 + r];

    size_t slab = (size_t)b * 16384;
    const f32x4* xs = reinterpret_cast<const f32x4*>(x + slab);
    f32x4* o2 = reinterpret_cast<f32x4*>(out + (size_t)67108864 + slab);

    for (int k = 0; k < 16; ++k) {
        int i = k * 8 + rg;
        int vidx = i * 32 + (t & 31);
        f32x4 v = xs[vidx];
        float h[8];
#pragma unroll
        for (int r = 0; r < 8; ++r) h[r] = hb[i * 8 + r];
        float t0 = 0.f, t1 = 0.f, t2 = 0.f, t3 = 0.f;
#pragma unroll
        for (int r = 0; r < 8; ++r) {
            t0 += h[r] * wreg[0][r];
            t1 += h[r] * wreg[1][r];
            t2 += h[r] * wreg[2][r];
            t3 += h[r] * wreg[3][r];
        }
        f32x4 y;
        y.x = fmaxf(v.x * t0, 0.f);
        y.y = fmaxf(v.y * t1, 0.f);
        y.z = fmaxf(v.z * t2, 0.f);
        y.w = fmaxf(v.w * t3, 0.f);
        __builtin_nontemporal_store(y, &o2[vidx]);
    }
}

extern "C" void kernel_launch(void* const* d_in, const int* in_sizes, int n_in,
                              void* d_out, int out_size, void* d_ws, size_t ws_size,
                              hipStream_t stream) {
    const float* x   = (const float*)d_in[0];
    const float* W1  = (const float*)d_in[1];
    const float* W2  = (const float*)d_in[2];
    const float* W3  = (const float*)d_in[3];
    const float* W4  = (const float*)d_in[4];
    const float* lam = (const float*)d_in[5];
    float* ws  = (float*)d_ws;
    float* out = (float*)d_out;

    bool use_bf = ws_size >= BF_WS_BYTES;

    k_init<<<33, 256, 0, stream>>>(ws);
    if (use_bf) {
        k_reduce<true><<<1024, 256, 0, stream>>>(x, out, ws);
        k_factors<<<17, 256, 0, stream>>>(W1, W2, W3, W4, lam, ws);
        k_output_bf<<<4096, 256, 0, stream>>>(ws, out);
    } else {
        k_reduce<false><<<1024, 256, 0, stream>>>(x, out, ws);
        k_factors<<<17, 256, 0, stream>>>(W1, W2, W3, W4, lam, ws);
        k_output_fp<<<4096, 256, 0, stream>>>(x, ws, out);
    }
}